// Round 5
// baseline (467.665 us; speedup 1.0000x reference)
//
#include <hip/hip_runtime.h>
#include <stdint.h>

#define NN 100000      // nodes
#define NE 1600000     // edges
#define MAXDEG 64      // Poisson(16): P(deg>64) ~ 1e-19, safe cap
#define NSLICE 8       // XCD count; blockIdx&7 ~ XCD (round-robin heuristic)
#define SLICE_SZ 12500 // nodes per build slice
#define CHUNK 6400     // edges per build block
#define NBLK 1563      // node-blocks of 64: ceil(NN/64)
#define GGRID 3128     // gather grid: ceil(NBLK/4)*8 (4 node-blocks per XCD-octet)

typedef __attribute__((ext_vector_type(8))) short short8;
typedef __attribute__((ext_vector_type(4))) float f32x4;

__device__ __forceinline__ float bflo(unsigned v) { return __uint_as_float(v << 16); }
__device__ __forceinline__ float bfhi(unsigned v) { return __uint_as_float(v & 0xffff0000u); }
__device__ __forceinline__ unsigned short f2bf(float f) {   // round-to-nearest-even
  unsigned u = __float_as_uint(f);
  u += 0x7fff + ((u >> 16) & 1);
  return (unsigned short)(u >> 16);
}

// ---- XCD-sliced bucket build (UNCHANGED, proven) ----
__global__ __launch_bounds__(256) void build_buckets(const int* __restrict__ src,
                                                     const int* __restrict__ dst,
                                                     int* __restrict__ cnt,
                                                     int* __restrict__ buck) {
  const int slice = blockIdx.x & (NSLICE - 1);
  const int chunk = blockIdx.x >> 3;
  const int c0 = chunk * CHUNK;
  const int lo = slice * SLICE_SZ, hi = lo + SLICE_SZ;
  for (int e = c0 + (int)threadIdx.x * 4; e < c0 + CHUNK; e += 1024) {
    int4 d = *(const int4*)(dst + e);
    int4 s = *(const int4*)(src + e);
    if (d.x >= lo && d.x < hi) { int p = atomicAdd(&cnt[d.x], 1); if (p < MAXDEG) buck[d.x * MAXDEG + p] = s.x; }
    if (d.y >= lo && d.y < hi) { int p = atomicAdd(&cnt[d.y], 1); if (p < MAXDEG) buck[d.y * MAXDEG + p] = s.y; }
    if (d.z >= lo && d.z < hi) { int p = atomicAdd(&cnt[d.z], 1); if (p < MAXDEG) buck[d.z * MAXDEG + p] = s.z; }
    if (d.w >= lo && d.w < hi) { int p = atomicAdd(&cnt[d.w], 1); if (p < MAXDEG) buck[d.w * MAXDEG + p] = s.w; }
  }
}

// ---- f32 -> packed bf16x2 (UNCHANGED, proven) ----
__global__ __launch_bounds__(256) void to_bf16(const float* __restrict__ x,
                                               unsigned* __restrict__ xb) {
  int i = blockIdx.x * 256 + threadIdx.x;     // over NN*32
  if (i >= NN * 32) return;
  float4 v = ((const float4*)x)[i];
  uint2 o;
  o.x = ((unsigned)f2bf(v.y) << 16) | f2bf(v.x);
  o.y = ((unsigned)f2bf(v.w) << 16) | f2bf(v.z);
  ((uint2*)xb)[i] = o;
}

// ---- one-time W transpose -> k-major bf16.
// WT1P[m][k], m in [0,256): m<128 -> W1l col m (px), m>=128 -> W1r col m-128 (r); k in [0,128)
// WT2P[m][k], m in [0,128): m<64 -> W2l col m (p2), m>=64 -> W2r col m-64 (out); k in [0,128)
__global__ __launch_bounds__(256) void transpose_w(const float* __restrict__ W1l,
                                                   const float* __restrict__ W1r,
                                                   const float* __restrict__ W2l,
                                                   const float* __restrict__ W2r,
                                                   unsigned short* __restrict__ WT1P,
                                                   unsigned short* __restrict__ WT2P) {
  int t = blockIdx.x * 256 + threadIdx.x;     // 192*256 = 49152 = 32768 + 16384
  if (t < 256 * 128) {
    int m = t >> 7, k = t & 127;
    float v = (m < 128) ? W1l[k * 128 + m] : W1r[k * 128 + (m - 128)];
    WT1P[t] = f2bf(v);
  } else {
    int i = t - 256 * 128;
    if (i < 128 * 128) {
      int m = i >> 7, k = i & 127;
      float v = (m < 64) ? W2l[k * 64 + m] : W2r[k * 64 + (m - 64)];
      WT2P[i] = f2bf(v);
    }
  }
}

// ---- proj1 (dense, streamed, modeled on proven proj2): per node,
// px = x@W1l (bf16 256B rows, IN-PLACE over xbf), r = x@W1r + b1 (bf16 256B rows).
// No relu here (applied after adding the mean in gather1).
__global__ __launch_bounds__(256) void proj1(const unsigned* __restrict__ xb,
                                             const unsigned short* __restrict__ WTP,
                                             const float* __restrict__ b1,
                                             unsigned short* __restrict__ px,
                                             unsigned short* __restrict__ r) {
  __shared__ unsigned short sA[64][264];          // 528B pitch (proven size)
  const int lane = threadIdx.x & 63, wv = threadIdx.x >> 6;
  const int nb = blockIdx.x * 64 + wv * 16;

  // stage my 16 x-rows (in-place safety: all reads before any store, wave-private)
#pragma unroll
  for (int i = 0; i < 16; i++) {
    int node = nb + i;
    unsigned v = (node < NN) ? xb[(size_t)node * 64 + lane] : 0u;
    ((unsigned*)&sA[wv * 16 + i][0])[lane] = v;
  }

  const int m = lane & 15, q = lane >> 4;
  f32x4 acc[16];
#pragma unroll
  for (int cc = 0; cc < 16; cc++) acc[cc] = {0.f, 0.f, 0.f, 0.f};
#pragma unroll
  for (int ks = 0; ks < 4; ks++) {                // K = 128
    short8 a = *(const short8*)&sA[wv * 16 + m][ks * 32 + q * 8];
#pragma unroll
    for (int cc = 0; cc < 16; cc++) {
      short8 b = *(const short8*)(WTP + (size_t)(cc * 16 + m) * 128 + ks * 32 + q * 8);
      acc[cc] = __builtin_amdgcn_mfma_f32_16x16x32_bf16(a, b, acc[cc], 0, 0, 0);
    }
  }

  // restage all 256 output cols (input cols dead after MFMA; wave-private rows)
#pragma unroll
  for (int cc = 0; cc < 16; cc++) {
    int col = cc * 16 + m;
    float bc = (col >= 128) ? b1[col - 128] : 0.f;
#pragma unroll
    for (int rr = 0; rr < 4; rr++) {
      int lr = wv * 16 + q * 4 + rr;
      sA[lr][col] = f2bf(acc[cc][rr] + bc);
    }
  }
  // store px (cols 0-127 -> bytes [0,256)) and r (cols 128-255 -> bytes [256,512))
#pragma unroll
  for (int it = 0; it < 4; it++) {
    int idx = it * 64 + lane;
    int rrow = idx >> 4, ck = idx & 15;           // 16 rows x 16 chunks of 16B
    int node = nb + rrow;
    if (node < NN) {
      uint4 v = *(const uint4*)((const char*)&sA[wv * 16 + rrow][0] + ck * 16);
      *(uint4*)((char*)(px + (size_t)node * 128) + ck * 16) = v;
    }
  }
#pragma unroll
  for (int it = 0; it < 4; it++) {
    int idx = it * 64 + lane;
    int rrow = idx >> 4, ck = idx & 15;
    int node = nb + rrow;
    if (node < NN) {
      uint4 v = *(const uint4*)((const char*)&sA[wv * 16 + rrow][0] + 256 + ck * 16);
      *(uint4*)((char*)(r + (size_t)node * 128) + ck * 16) = v;
    }
  }
}

// ---- gather1: h = relu(mean_j px_j + r), channel-half per XCD quad.
// half = (blockIdx&7)>>2: XCDs 0-3 do ch[0,64), 4-7 do ch[64,128) -> each px line
// filled by only 4 XCDs. Inner loop = proven gather_add shape (2 edges/load).
// h written IN-PLACE over r (per-node read-before-write, wave-private).
__global__ __launch_bounds__(256) void gather1(const unsigned short* __restrict__ px,
                                               const unsigned short* __restrict__ rt,
                                               const int* __restrict__ cnt,
                                               const int* __restrict__ buck,
                                               unsigned short* __restrict__ h) {
  const int b = blockIdx.x;
  const int xcd = b & 7;
  const int half = xcd >> 2;
  const int nbi = (b >> 3) * 4 + (xcd & 3);
  if (nbi >= NBLK) return;
  const int lane = threadIdx.x & 63, wv = threadIdx.x >> 6;
  const int nb = nbi * 64 + wv * 16;
  const int g = lane >> 5, c = lane & 31;
  const unsigned* pxw = (const unsigned*)px;      // row = 64 u32 (256B)

  int slot[16]; int deg[16]; unsigned rr[16];
#pragma unroll
  for (int i = 0; i < 16; i++) {
    int node = nb + i;
    if (node < NN) {
      slot[i] = buck[(size_t)node * MAXDEG + (lane & 31)];   // first 128B only
      deg[i]  = cnt[node];
      rr[i]   = ((const unsigned*)rt)[(size_t)node * 64 + half * 32 + c];
    } else { slot[i] = 0; deg[i] = 0; rr[i] = 0u; }
  }

#pragma unroll
  for (int i = 0; i < 16; i++) {
    float a0 = 0.f, a1 = 0.f;
    int node = nb + i;
    int d = min(deg[i], MAXDEG);
    if (d > 32) {                                 // rare (P ~ 2e-4): fetch slots 32-63
      if (lane >= 32) slot[i] = buck[(size_t)node * MAXDEG + lane];
    }
    if (d > 0) {                                  // wave-uniform
      int last = d - 1;
      for (int p = 0; p < d; p += 16) {           // 16 edges per chunk, 8 loads
        unsigned v[8];
#pragma unroll
        for (int j = 0; j < 8; j++) {
          int e = p + 2 * j + g;
          int s = __shfl(slot[i], e < last ? e : last, 64);
          v[j] = pxw[(size_t)s * 64 + half * 32 + c];        // 128B half-row
        }
#pragma unroll
        for (int j = 0; j < 8; j++) {
          int e = p + 2 * j + g;
          unsigned w = (e <= last) ? v[j] : 0u;
          a0 += bflo(w); a1 += bfhi(w);
        }
      }
      a0 += __shfl_xor(a0, 32, 64);
      a1 += __shfl_xor(a1, 32, 64);
    }
    if (node < NN && lane < 32) {
      float inv = 1.f / (float)max(deg[i], 1);
      float h0 = fmaxf(a0 * inv + bflo(rr[i]), 0.f);
      float h1 = fmaxf(a1 * inv + bfhi(rr[i]), 0.f);
      ((unsigned*)h)[(size_t)node * 64 + half * 32 + c] =
          ((unsigned)f2bf(h1) << 16) | f2bf(h0);
    }
  }
}

// ---- proj2 (proven R4 shape + split p-store): p2 = h@W2l (two 32-ch 64B-row
// tables), out = h@W2r + b2 (f32 256B rows, written directly).
__global__ __launch_bounds__(256) void proj2(const unsigned* __restrict__ hb,
                                             const unsigned short* __restrict__ WTP,
                                             const float* __restrict__ b2,
                                             unsigned short* __restrict__ p2,
                                             float* __restrict__ out) {
  __shared__ unsigned short sA[64][136];          // 272B pitch
  const int lane = threadIdx.x & 63, wv = threadIdx.x >> 6;
  const int nb = blockIdx.x * 64 + wv * 16;

#pragma unroll
  for (int i = 0; i < 16; i++) {
    int node = nb + i;
    unsigned v = (node < NN) ? hb[(size_t)node * 64 + lane] : 0u;
    ((unsigned*)&sA[wv * 16 + i][0])[lane] = v;
  }

  const int m = lane & 15, q = lane >> 4;
  f32x4 acc[8];
#pragma unroll
  for (int cc = 0; cc < 8; cc++) acc[cc] = {0.f, 0.f, 0.f, 0.f};
#pragma unroll
  for (int ks = 0; ks < 4; ks++) {                // K = 128
    short8 a = *(const short8*)&sA[wv * 16 + m][ks * 32 + q * 8];
#pragma unroll
    for (int cc = 0; cc < 8; cc++) {
      short8 b = *(const short8*)(WTP + (size_t)(cc * 16 + m) * 128 + ks * 32 + q * 8);
      acc[cc] = __builtin_amdgcn_mfma_f32_16x16x32_bf16(a, b, acc[cc], 0, 0, 0);
    }
  }

  // p-half (cols 0..63 = h@W2l): restage bf16, store as two 32-ch tables
#pragma unroll
  for (int cc = 0; cc < 4; cc++) {
    int col = cc * 16 + m;
#pragma unroll
    for (int rr = 0; rr < 4; rr++) {
      int lr = wv * 16 + q * 4 + rr;
      sA[lr][col] = f2bf(acc[cc][rr]);
    }
  }
  {
    int rrow = lane >> 2, ck = lane & 3;          // 16 rows x 4 chunks of 16B
    int node = nb + rrow;
    if (node < NN) {
      uint4 vlo = *(const uint4*)((const char*)&sA[wv * 16 + rrow][0] + ck * 16);
      *(uint4*)((char*)(p2 + (size_t)node * 32) + ck * 16) = vlo;
      uint4 vhi = *(const uint4*)((const char*)&sA[wv * 16 + rrow][0] + 64 + ck * 16);
      *(uint4*)((char*)(p2 + (size_t)NN * 32 + (size_t)node * 32) + ck * 16) = vhi;
    }
  }
  // out-half (cols 64..127 = h@W2r + b2): restage f32, store 256B rows
#pragma unroll
  for (int cc = 4; cc < 8; cc++) {
    int col = (cc - 4) * 16 + m;
    float bc = b2[col];
#pragma unroll
    for (int rr = 0; rr < 4; rr++) {
      int lr = wv * 16 + q * 4 + rr;
      ((float*)&sA[lr][0])[col] = acc[cc][rr] + bc;
    }
  }
#pragma unroll
  for (int it = 0; it < 4; it++) {
    int idx = it * 64 + lane;
    int rrow = idx >> 4, ck = idx & 15;
    int node = nb + rrow;
    if (node < NN) {
      uint4 v = *(const uint4*)((const char*)&sA[wv * 16 + rrow][0] + ck * 16);
      *(uint4*)((char*)(out + (size_t)node * 64) + ck * 16) = v;
    }
  }
}

// ---- gather2: out[ch-half] += mean_j p2_j. 32-ch tables, 64B rows ->
// 4 edges/load (R2-proven inner form). Same XCD-quad channel split.
__global__ __launch_bounds__(256) void gather2(const unsigned short* __restrict__ p2,
                                               const int* __restrict__ cnt,
                                               const int* __restrict__ buck,
                                               float* __restrict__ out) {
  const int b = blockIdx.x;
  const int xcd = b & 7;
  const int half = xcd >> 2;
  const int nbi = (b >> 3) * 4 + (xcd & 3);
  if (nbi >= NBLK) return;
  const int lane = threadIdx.x & 63, wv = threadIdx.x >> 6;
  const int nb = nbi * 64 + wv * 16;
  const int sub = lane >> 4, cl = lane & 15;      // 4 edges/load, 16 lanes/edge
  const unsigned* pw = (const unsigned*)(p2 + (size_t)half * NN * 32);   // row = 16 u32

  int slot[16]; int deg[16];
#pragma unroll
  for (int i = 0; i < 16; i++) {
    int node = nb + i;
    if (node < NN) {
      slot[i] = buck[(size_t)node * MAXDEG + (lane & 31)];
      deg[i]  = cnt[node];
    } else { slot[i] = 0; deg[i] = 0; }
  }

#pragma unroll
  for (int i = 0; i < 16; i++) {
    float a0 = 0.f, a1 = 0.f;
    int node = nb + i;
    int d = min(deg[i], MAXDEG);
    if (d > 32) {
      if (lane >= 32) slot[i] = buck[(size_t)node * MAXDEG + lane];
    }
    if (d > 0) {                                  // wave-uniform
      int last = d - 1;
      for (int p = 0; p < d; p += 16) {           // 16 edges per chunk, 4 loads
        unsigned v[4];
#pragma unroll
        for (int j = 0; j < 4; j++) {
          int e = p + 4 * j + sub;
          int s = __shfl(slot[i], e < last ? e : last, 64);
          v[j] = pw[(size_t)s * 16 + cl];         // 64B row
        }
#pragma unroll
        for (int j = 0; j < 4; j++) {
          int e = p + 4 * j + sub;
          unsigned w = (e <= last) ? v[j] : 0u;
          a0 += bflo(w); a1 += bfhi(w);
        }
      }
      a0 += __shfl_xor(a0, 16, 64);
      a0 += __shfl_xor(a0, 32, 64);
      a1 += __shfl_xor(a1, 16, 64);
      a1 += __shfl_xor(a1, 32, 64);
    }
    if (node < NN && lane < 16) {
      float inv = 1.f / (float)max(deg[i], 1);
      float2* fp = (float2*)(out + (size_t)node * 64 + half * 32 + cl * 2);
      float2 tv = *fp;
      tv.x += a0 * inv; tv.y += a1 * inv;
      *fp = tv;
    }
  }
}

extern "C" void kernel_launch(void* const* d_in, const int* in_sizes, int n_in,
                              void* d_out, int out_size, void* d_ws, size_t ws_size,
                              hipStream_t stream) {
  const float* x   = (const float*)d_in[0];
  const int*   ei  = (const int*)d_in[1];
  const float* W1l = (const float*)d_in[2];
  const float* b1  = (const float*)d_in[3];
  const float* W1r = (const float*)d_in[4];
  const float* W2l = (const float*)d_in[5];
  const float* b2  = (const float*)d_in[6];
  const float* W2r = (const float*)d_in[7];
  float* out = (float*)d_out;

  // ws (proven 77.4MB footprint):
  // cnt 0.5 | buck 25.6 | R1 25.6: xbf -> px(in-place) -> p2(after L1) |
  // R2 25.6: r -> h(in-place) | WT1P 64K | WT2P 32K
  char* ws = (char*)d_ws;
  int* cnt  = (int*)ws;                                   ws += (512 << 10);
  int* buck = (int*)ws;                                   ws += (size_t)NN * MAXDEG * 4;
  unsigned* xbf = (unsigned*)ws;                          ws += (size_t)NN * 64 * 4;
  unsigned short* rh = (unsigned short*)ws;               ws += (size_t)NN * 128 * 2;
  unsigned short* WT1P = (unsigned short*)ws;             ws += 256 * 128 * 2;
  unsigned short* WT2P = (unsigned short*)ws;             ws += 128 * 128 * 2;
  unsigned short* px = (unsigned short*)xbf;  // in-place over xbf after proj1
  unsigned short* p2 = (unsigned short*)xbf;  // over dead px after gather1

  const int* src = ei;        // edge_index[0]
  const int* dst = ei + NE;   // edge_index[1]

  hipMemsetAsync(cnt, 0, (size_t)NN * 4, stream);
  build_buckets<<<NSLICE * (NE / CHUNK), 256, 0, stream>>>(src, dst, cnt, buck);
  to_bf16<<<(NN * 32 + 255) / 256, 256, 0, stream>>>(x, xbf);
  transpose_w<<<192, 256, 0, stream>>>(W1l, W1r, W2l, W2r, WT1P, WT2P);

  // layer 1: px = x@W1l, r = x@W1r + b1; h = relu(mean(px) + r)
  proj1<<<NBLK, 256, 0, stream>>>(xbf, WT1P, b1, px, rh);
  gather1<<<GGRID, 256, 0, stream>>>(px, rh, cnt, buck, rh);

  // layer 2: p2 = h@W2l (split 32-ch tables), out = h@W2r + b2; out += mean(p2)
  proj2<<<NBLK, 256, 0, stream>>>((const unsigned*)rh, WT2P, b2, p2, out);
  gather2<<<GGRID, 256, 0, stream>>>(p2, cnt, buck, out);
}

// Round 6
// 400.702 us; speedup vs baseline: 1.1671x; 1.1671x over previous
//
#include <hip/hip_runtime.h>
#include <stdint.h>

#define NN 100000      // nodes
#define NE 1600000     // edges
#define MAXDEG 64      // Poisson(16): P(deg>64) ~ 1e-19, safe cap
#define NSLICE 8       // XCD count; blockIdx&7 ~ XCD (round-robin heuristic)
#define SLICE_SZ 12500 // nodes per build slice
#define CHUNK 6400     // edges per build block
#define NBLK 1563      // node-blocks of 64: ceil(NN/64)
#define GGRID 3128     // split-gather grid: 391 octets x 8 (4 node-blocks x 2 halves)

#define BB_BLOCKS 2000           // NSLICE * (NE/CHUNK)
#define TB_BLOCKS 12500          // NN*32/256 exactly
#define TW_BLOCKS 192
#define PREP_BLOCKS (BB_BLOCKS + TB_BLOCKS + TW_BLOCKS)

typedef __attribute__((ext_vector_type(8))) short short8;
typedef __attribute__((ext_vector_type(4))) float f32x4;

__device__ __forceinline__ float bflo(unsigned v) { return __uint_as_float(v << 16); }
__device__ __forceinline__ float bfhi(unsigned v) { return __uint_as_float(v & 0xffff0000u); }
__device__ __forceinline__ unsigned short f2bf(float f) {   // round-to-nearest-even
  unsigned u = __float_as_uint(f);
  u += 0x7fff + ((u >> 16) & 1);
  return (unsigned short)(u >> 16);
}

// ---- merged prep: [0,2000) bucket build | [2000,14500) bf16 convert | [14500,14692) W transpose.
// The three phases are data-independent; merging saves launch gaps and hides the
// streaming conversion under the build's latency stalls.
__global__ __launch_bounds__(256) void prep(const int* __restrict__ src,
                                            const int* __restrict__ dst,
                                            int* __restrict__ cnt,
                                            int* __restrict__ buck,
                                            const float* __restrict__ x,
                                            unsigned* __restrict__ xb,
                                            const float* __restrict__ W1l,
                                            const float* __restrict__ W1r,
                                            const float* __restrict__ W2l,
                                            const float* __restrict__ W2r,
                                            unsigned short* __restrict__ WT1,
                                            unsigned short* __restrict__ WT2p) {
  const int b = blockIdx.x;
  if (b < BB_BLOCKS) {
    // ---- XCD-sliced bucket build (verbatim-proven) ----
    const int slice = b & (NSLICE - 1);
    const int chunk = b >> 3;
    const int c0 = chunk * CHUNK;
    const int lo = slice * SLICE_SZ, hi = lo + SLICE_SZ;
    for (int e = c0 + (int)threadIdx.x * 4; e < c0 + CHUNK; e += 1024) {
      int4 d = *(const int4*)(dst + e);
      int4 s = *(const int4*)(src + e);
      if (d.x >= lo && d.x < hi) { int p = atomicAdd(&cnt[d.x], 1); if (p < MAXDEG) buck[d.x * MAXDEG + p] = s.x; }
      if (d.y >= lo && d.y < hi) { int p = atomicAdd(&cnt[d.y], 1); if (p < MAXDEG) buck[d.y * MAXDEG + p] = s.y; }
      if (d.z >= lo && d.z < hi) { int p = atomicAdd(&cnt[d.z], 1); if (p < MAXDEG) buck[d.z * MAXDEG + p] = s.z; }
      if (d.w >= lo && d.w < hi) { int p = atomicAdd(&cnt[d.w], 1); if (p < MAXDEG) buck[d.w * MAXDEG + p] = s.w; }
    }
  } else if (b < BB_BLOCKS + TB_BLOCKS) {
    // ---- f32 -> packed bf16x2 (verbatim-proven; 12500*256 == NN*32 exactly) ----
    int i = (b - BB_BLOCKS) * 256 + threadIdx.x;
    float4 v = ((const float4*)x)[i];
    uint2 o;
    o.x = ((unsigned)f2bf(v.y) << 16) | f2bf(v.x);
    o.y = ((unsigned)f2bf(v.w) << 16) | f2bf(v.z);
    ((uint2*)xb)[i] = o;
  } else {
    // ---- W transpose -> k-major bf16 (verbatim R4-proven) ----
    // WT1[m][k], m in [0,128), k = [W1l rows | W1r rows] (256 k)
    // WT2p[m][k], m in [0,128): m<64 -> W2l col m, m>=64 -> W2r col m-64; k in [0,128)
    int t = (b - BB_BLOCKS - TB_BLOCKS) * 256 + threadIdx.x;
    if (t < 128 * 256) {
      int m = t >> 8, k = t & 255;
      float v = (k < 128) ? W1l[k * 128 + m] : W1r[(k - 128) * 128 + m];
      WT1[t] = f2bf(v);
    } else {
      int i = t - 128 * 256;
      if (i < 128 * 128) {
        int m = i >> 7, k = i & 127;
        float v = (m < 64) ? W2l[k * 64 + m] : W2r[k * 64 + (m - 64)];
        WT2p[i] = f2bf(v);
      }
    }
  }
}

// ---- FUSED layer 1 (CHAMPION R0 kernel, verbatim): gather-mean into LDS, MFMA.
// Barrier-free: wave wv owns sA rows [wv*16, wv*16+16) exclusively.
template <int M, bool RELU, typename OutT>
__global__ __launch_bounds__(256) void sage_fused(const unsigned* __restrict__ xb,
                                                  const int* __restrict__ cnt,
                                                  const int* __restrict__ buck,
                                                  const unsigned short* __restrict__ WT,
                                                  const float* __restrict__ bias,
                                                  OutT* __restrict__ out) {
  constexpr int LDA = 264;                       // +8 bf16 pad; 528B pitch
  __shared__ unsigned short sA[64][LDA];

  const int t = threadIdx.x;
  const int lane = t & 63;
  const int wv = t >> 6;
  const int node0 = blockIdx.x * 64;
  const int nb = node0 + wv * 16;                // this wave's 16 nodes

  // ---- prefetch: 16 bucket rows + 16 x rows + 16 degrees (all independent) ----
  int slot[16]; unsigned xr[16]; int deg[16];
#pragma unroll
  for (int i = 0; i < 16; i++) {
    int node = nb + i;
    if (node < NN) {                             // lane-uniform branch
      slot[i] = buck[(size_t)node * MAXDEG + lane];
      xr[i]   = xb[(size_t)node * 64 + lane];
      deg[i]  = cnt[node];
    } else { slot[i] = 0; xr[i] = 0u; deg[i] = 0; }
  }

  // ---- gather-mean each of my 16 rows into wave-private LDS ----
#pragma unroll
  for (int i = 0; i < 16; i++) {
    float a0 = 0.f, a1 = 0.f;
    int dcl = min(deg[i], MAXDEG);
    if (dcl > 0) {                               // wave-uniform
      int last = dcl - 1;
      for (int p = 0; p < dcl; p += 16) {
        unsigned v[16];
#pragma unroll
        for (int j = 0; j < 16; j++) {
          int s = __shfl(slot[i], min(p + j, last), 64);
          v[j] = xb[(size_t)s * 64 + lane];      // 256B/row coalesced, no branch
        }
#pragma unroll
        for (int j = 0; j < 16; j++) {
          unsigned vj = (p + j <= last) ? v[j] : 0u;
          a0 += bflo(vj); a1 += bfhi(vj);
        }
      }
    }
    float inv = 1.f / (float)max(deg[i], 1);
    unsigned pk = ((unsigned)f2bf(a1 * inv) << 16) | f2bf(a0 * inv);
    ((unsigned*)&sA[wv * 16 + i][0])[lane]   = pk;      // agg half: k in [0,128)
    ((unsigned*)&sA[wv * 16 + i][128])[lane] = xr[i];   // x half:   k in [128,256)
  }

  // ---- MFMA: A from my LDS rows, B from k-major WT in global (L2-hot) ----
  const int m = lane & 15;
  const int q = lane >> 4;

  f32x4 acc[M / 16];
#pragma unroll
  for (int c = 0; c < M / 16; c++) acc[c] = {0.f, 0.f, 0.f, 0.f};

#pragma unroll
  for (int ks = 0; ks < 8; ks++) {
    short8 a = *(const short8*)&sA[wv * 16 + m][ks * 32 + q * 8];   // A[m][q*8+j]
#pragma unroll
    for (int c = 0; c < M / 16; c++) {
      // B[k=q*8+j][n=c*16+m] = WT[n][k], contiguous 16B in k
      short8 b = *(const short8*)(WT + (size_t)(c * 16 + m) * 256 + ks * 32 + q * 8);
      acc[c] = __builtin_amdgcn_mfma_f32_16x16x32_bf16(a, b, acc[c], 0, 0, 0);
    }
  }

  // ---- epilogue: restage C through my (dead) sA rows -> full-line stores ----
#pragma unroll
  for (int c = 0; c < M / 16; c++) {
    int col = c * 16 + m;
    float bc = bias[col];
#pragma unroll
    for (int r = 0; r < 4; r++) {
      int lr = wv * 16 + q * 4 + r;               // D[row=q*4+r][col=m]
      float v = acc[c][r] + bc;
      if (RELU) v = fmaxf(v, 0.f);
      if constexpr (sizeof(OutT) == 2) sA[lr][col] = f2bf(v);
      else ((float*)&sA[lr][0])[col] = v;
    }
  }
#pragma unroll
  for (int it = 0; it < 4; it++) {
    int idx = it * 64 + lane;                     // 16 rows x 16 chunks of 16B
    int rr = idx >> 4, cc = idx & 15;
    int node = node0 + wv * 16 + rr;
    if (node < NN) {
      uint4 v = *(const uint4*)((const char*)&sA[wv * 16 + rr][0] + cc * 16);
      *(uint4*)((char*)(out + (size_t)node * M) + cc * 16) = v;
    }
  }
}

// ---- layer-2 pre-projection (R5-verbatim, correctness-proven): p2 = h@W2l as two
// 32-ch 64B-row tables; out = h@W2r + b2 (f32 256B rows, written directly).
__global__ __launch_bounds__(256) void proj2(const unsigned* __restrict__ hb,
                                             const unsigned short* __restrict__ WTP,
                                             const float* __restrict__ b2,
                                             unsigned short* __restrict__ p2,
                                             float* __restrict__ out) {
  __shared__ unsigned short sA[64][136];          // 272B pitch
  const int lane = threadIdx.x & 63, wv = threadIdx.x >> 6;
  const int nb = blockIdx.x * 64 + wv * 16;

#pragma unroll
  for (int i = 0; i < 16; i++) {
    int node = nb + i;
    unsigned v = (node < NN) ? hb[(size_t)node * 64 + lane] : 0u;
    ((unsigned*)&sA[wv * 16 + i][0])[lane] = v;
  }

  const int m = lane & 15, q = lane >> 4;
  f32x4 acc[8];
#pragma unroll
  for (int cc = 0; cc < 8; cc++) acc[cc] = {0.f, 0.f, 0.f, 0.f};
#pragma unroll
  for (int ks = 0; ks < 4; ks++) {                // K = 128
    short8 a = *(const short8*)&sA[wv * 16 + m][ks * 32 + q * 8];
#pragma unroll
    for (int cc = 0; cc < 8; cc++) {
      short8 b = *(const short8*)(WTP + (size_t)(cc * 16 + m) * 128 + ks * 32 + q * 8);
      acc[cc] = __builtin_amdgcn_mfma_f32_16x16x32_bf16(a, b, acc[cc], 0, 0, 0);
    }
  }

  // p-half (cols 0..63 = h@W2l): restage bf16, store as two 32-ch tables
#pragma unroll
  for (int cc = 0; cc < 4; cc++) {
    int col = cc * 16 + m;
#pragma unroll
    for (int rr = 0; rr < 4; rr++) {
      int lr = wv * 16 + q * 4 + rr;
      sA[lr][col] = f2bf(acc[cc][rr]);
    }
  }
  {
    int rrow = lane >> 2, ck = lane & 3;          // 16 rows x 4 chunks of 16B
    int node = nb + rrow;
    if (node < NN) {
      uint4 vlo = *(const uint4*)((const char*)&sA[wv * 16 + rrow][0] + ck * 16);
      *(uint4*)((char*)(p2 + (size_t)node * 32) + ck * 16) = vlo;
      uint4 vhi = *(const uint4*)((const char*)&sA[wv * 16 + rrow][0] + 64 + ck * 16);
      *(uint4*)((char*)(p2 + (size_t)NN * 32 + (size_t)node * 32) + ck * 16) = vhi;
    }
  }
  // out-half (cols 64..127 = h@W2r + b2): restage f32, store 256B rows
#pragma unroll
  for (int cc = 4; cc < 8; cc++) {
    int col = (cc - 4) * 16 + m;
    float bc = b2[col];
#pragma unroll
    for (int rr = 0; rr < 4; rr++) {
      int lr = wv * 16 + q * 4 + rr;
      ((float*)&sA[lr][0])[col] = acc[cc][rr] + bc;
    }
  }
#pragma unroll
  for (int it = 0; it < 4; it++) {
    int idx = it * 64 + lane;
    int rrow = idx >> 4, ck = idx & 15;
    int node = nb + rrow;
    if (node < NN) {
      uint4 v = *(const uint4*)((const char*)&sA[wv * 16 + rrow][0] + ck * 16);
      *(uint4*)((char*)(out + (size_t)node * 64) + ck * 16) = v;
    }
  }
}

// ---- gather2 (R5-verbatim, correctness-proven): out[ch-half] += mean_j p2_j.
// 32-ch 64B-row tables, 4 edges/load, XCD-quad channel split.
__global__ __launch_bounds__(256) void gather2(const unsigned short* __restrict__ p2,
                                               const int* __restrict__ cnt,
                                               const int* __restrict__ buck,
                                               float* __restrict__ out) {
  const int b = blockIdx.x;
  const int xcd = b & 7;
  const int half = xcd >> 2;
  const int nbi = (b >> 3) * 4 + (xcd & 3);
  if (nbi >= NBLK) return;
  const int lane = threadIdx.x & 63, wv = threadIdx.x >> 6;
  const int nb = nbi * 64 + wv * 16;
  const int sub = lane >> 4, cl = lane & 15;      // 4 edges/load, 16 lanes/edge
  const unsigned* pw = (const unsigned*)(p2 + (size_t)half * NN * 32);   // row = 16 u32

  int slot[16]; int deg[16];
#pragma unroll
  for (int i = 0; i < 16; i++) {
    int node = nb + i;
    if (node < NN) {
      slot[i] = buck[(size_t)node * MAXDEG + (lane & 31)];
      deg[i]  = cnt[node];
    } else { slot[i] = 0; deg[i] = 0; }
  }

#pragma unroll
  for (int i = 0; i < 16; i++) {
    float a0 = 0.f, a1 = 0.f;
    int node = nb + i;
    int d = min(deg[i], MAXDEG);
    if (d > 32) {                                 // rare: fetch slots 32-63
      if (lane >= 32) slot[i] = buck[(size_t)node * MAXDEG + lane];
    }
    if (d > 0) {                                  // wave-uniform
      int last = d - 1;
      for (int p = 0; p < d; p += 16) {           // 16 edges per chunk, 4 loads
        unsigned v[4];
#pragma unroll
        for (int j = 0; j < 4; j++) {
          int e = p + 4 * j + sub;
          int s = __shfl(slot[i], e < last ? e : last, 64);
          v[j] = pw[(size_t)s * 16 + cl];         // 64B row
        }
#pragma unroll
        for (int j = 0; j < 4; j++) {
          int e = p + 4 * j + sub;
          unsigned w = (e <= last) ? v[j] : 0u;
          a0 += bflo(w); a1 += bfhi(w);
        }
      }
      a0 += __shfl_xor(a0, 16, 64);
      a0 += __shfl_xor(a0, 32, 64);
      a1 += __shfl_xor(a1, 16, 64);
      a1 += __shfl_xor(a1, 32, 64);
    }
    if (node < NN && lane < 16) {
      float inv = 1.f / (float)max(deg[i], 1);
      float2* fp = (float2*)(out + (size_t)node * 64 + half * 32 + cl * 2);
      float2 tv = *fp;
      tv.x += a0 * inv; tv.y += a1 * inv;
      *fp = tv;
    }
  }
}

extern "C" void kernel_launch(void* const* d_in, const int* in_sizes, int n_in,
                              void* d_out, int out_size, void* d_ws, size_t ws_size,
                              hipStream_t stream) {
  const float* x   = (const float*)d_in[0];
  const int*   ei  = (const int*)d_in[1];
  const float* W1l = (const float*)d_in[2];
  const float* b1  = (const float*)d_in[3];
  const float* W1r = (const float*)d_in[4];
  const float* W2l = (const float*)d_in[5];
  const float* b2  = (const float*)d_in[6];
  const float* W2r = (const float*)d_in[7];
  float* out = (float*)d_out;

  // ws (proven 77.4MB footprint):
  // cnt 0.5 | buck 25.6 | xbf 25.6 (p2 aliases after L1) | hb 25.6 | WT1 64K | WT2p 32K
  char* ws = (char*)d_ws;
  int* cnt  = (int*)ws;                                   ws += (512 << 10);
  int* buck = (int*)ws;                                   ws += (size_t)NN * MAXDEG * 4;
  unsigned* xbf = (unsigned*)ws;                          ws += (size_t)NN * 64 * 4;
  unsigned* hb = (unsigned*)ws;                           ws += (size_t)NN * 64 * 4;
  unsigned short* WT1 = (unsigned short*)ws;              ws += 128 * 256 * 2;
  unsigned short* WT2p = (unsigned short*)ws;             ws += 128 * 128 * 2;
  unsigned short* p2 = (unsigned short*)xbf;  // alias: x table dead after layer 1

  const int* src = ei;        // edge_index[0]
  const int* dst = ei + NE;   // edge_index[1]

  hipMemsetAsync(cnt, 0, (size_t)NN * 4, stream);
  prep<<<PREP_BLOCKS, 256, 0, stream>>>(src, dst, cnt, buck, x, xbf,
                                        W1l, W1r, W2l, W2r, WT1, WT2p);

  // layer 1: h = relu([mean|x] @ [W1l;W1r] + b1), bf16 (champion fused kernel)
  sage_fused<128, true, unsigned short><<<NBLK, 256, 0, stream>>>(
      xbf, cnt, buck, WT1, b1, (unsigned short*)hb);

  // layer 2a: p2 = h@W2l (two 32-ch 64B-row tables), out = h@W2r + b2
  proj2<<<NBLK, 256, 0, stream>>>(hb, WT2p, b2, p2, out);

  // layer 2b: out += mean-gather(p2), XCD-quad channel split
  gather2<<<GGRID, 256, 0, stream>>>(p2, cnt, buck, out);
}

// Round 7
// 376.719 us; speedup vs baseline: 1.2414x; 1.0637x over previous
//
#include <hip/hip_runtime.h>
#include <stdint.h>

#define NN 100000      // nodes
#define NE 1600000     // edges
#define MAXDEG 64      // Poisson(16): P(deg>64) ~ 1e-19, safe cap
#define NSLICE 8       // XCD count; slice = blockIdx & 7 (perf heuristic only)
#define SLICE_SZ 12500 // nodes per slice
#define CHUNK 6400     // edges per block; NE/CHUNK = 250 chunks per slice

typedef __attribute__((ext_vector_type(8))) short short8;
typedef __attribute__((ext_vector_type(4))) float f32x4;

__device__ __forceinline__ float bflo(unsigned v) { return __uint_as_float(v << 16); }
__device__ __forceinline__ float bfhi(unsigned v) { return __uint_as_float(v & 0xffff0000u); }
__device__ __forceinline__ unsigned short f2bf(float f) {   // round-to-nearest-even
  unsigned u = __float_as_uint(f);
  u += 0x7fff + ((u >> 16) & 1);
  return (unsigned short)(u >> 16);
}

// ---- XCD-sliced bucket build: per-XCD write region 3.2MB -> L2-resident ----
__global__ __launch_bounds__(256) void build_buckets(const int* __restrict__ src,
                                                     const int* __restrict__ dst,
                                                     int* __restrict__ cnt,
                                                     int* __restrict__ buck) {
  const int slice = blockIdx.x & (NSLICE - 1);
  const int chunk = blockIdx.x >> 3;
  const int c0 = chunk * CHUNK;
  const int lo = slice * SLICE_SZ, hi = lo + SLICE_SZ;
  for (int e = c0 + (int)threadIdx.x * 4; e < c0 + CHUNK; e += 1024) {
    int4 d = *(const int4*)(dst + e);
    int4 s = *(const int4*)(src + e);
    if (d.x >= lo && d.x < hi) { int p = atomicAdd(&cnt[d.x], 1); if (p < MAXDEG) buck[d.x * MAXDEG + p] = s.x; }
    if (d.y >= lo && d.y < hi) { int p = atomicAdd(&cnt[d.y], 1); if (p < MAXDEG) buck[d.y * MAXDEG + p] = s.y; }
    if (d.z >= lo && d.z < hi) { int p = atomicAdd(&cnt[d.z], 1); if (p < MAXDEG) buck[d.z * MAXDEG + p] = s.z; }
    if (d.w >= lo && d.w < hi) { int p = atomicAdd(&cnt[d.w], 1); if (p < MAXDEG) buck[d.w * MAXDEG + p] = s.w; }
  }
}

// ---- f32 -> packed bf16x2 (float4 per thread) ----
__global__ __launch_bounds__(256) void to_bf16(const float* __restrict__ x,
                                               unsigned* __restrict__ xb) {
  int i = blockIdx.x * 256 + threadIdx.x;     // over NN*32
  if (i >= NN * 32) return;
  float4 v = ((const float4*)x)[i];
  uint2 o;
  o.x = ((unsigned)f2bf(v.y) << 16) | f2bf(v.x);
  o.y = ((unsigned)f2bf(v.w) << 16) | f2bf(v.z);
  ((uint2*)xb)[i] = o;
}

// ---- one-time W transpose -> k-major bf16: WT[m][k], k = [Wl rows | Wr rows] ----
__global__ __launch_bounds__(256) void transpose_w(const float* __restrict__ W1l,
                                                   const float* __restrict__ W1r,
                                                   const float* __restrict__ W2l,
                                                   const float* __restrict__ W2r,
                                                   unsigned short* __restrict__ WT1,
                                                   unsigned short* __restrict__ WT2) {
  int t = blockIdx.x * 256 + threadIdx.x;
  if (t < 128 * 256) {
    int m = t >> 8, k = t & 255;
    float v = (k < 128) ? W1l[k * 128 + m] : W1r[(k - 128) * 128 + m];
    WT1[t] = f2bf(v);
  } else {
    int i = t - 128 * 256;
    if (i < 64 * 256) {
      int m = i >> 8, k = i & 255;
      float v = (k < 128) ? W2l[k * 64 + m] : W2r[(k - 128) * 64 + m];
      WT2[i] = f2bf(v);
    }
  }
}

// ---- FUSED layer: gather-mean directly into LDS, then MFMA. BARRIER-FREE:
// wave wv owns sA rows [wv*16, wv*16+16) exclusively (writes them in the
// gather phase, reads them as A-fragments and epilogue staging). Per-wave DS
// ordering makes write->read safe without __syncthreads.
template <int M, bool RELU, typename OutT>
__global__ __launch_bounds__(256) void sage_fused(const unsigned* __restrict__ xb,
                                                  const int* __restrict__ cnt,
                                                  const int* __restrict__ buck,
                                                  const unsigned short* __restrict__ WT,
                                                  const float* __restrict__ bias,
                                                  OutT* __restrict__ out) {
  constexpr int LDA = 264;                       // +8 bf16 pad; 528B pitch
  __shared__ unsigned short sA[64][LDA];

  const int t = threadIdx.x;
  const int lane = t & 63;
  const int wv = t >> 6;
  const int node0 = blockIdx.x * 64;
  const int nb = node0 + wv * 16;                // this wave's 16 nodes

  // ---- prefetch: 16 bucket rows + 16 x rows + 16 degrees (all independent) ----
  int slot[16]; unsigned xr[16]; int deg[16];
#pragma unroll
  for (int i = 0; i < 16; i++) {
    int node = nb + i;
    if (node < NN) {                             // lane-uniform branch
      slot[i] = buck[(size_t)node * MAXDEG + lane];
      xr[i]   = xb[(size_t)node * 64 + lane];
      deg[i]  = cnt[node];
    } else { slot[i] = 0; xr[i] = 0u; deg[i] = 0; }
  }

  // ---- gather-mean each of my 16 rows into wave-private LDS ----
#pragma unroll
  for (int i = 0; i < 16; i++) {
    float a0 = 0.f, a1 = 0.f;
    int dcl = min(deg[i], MAXDEG);
    if (dcl > 0) {                               // wave-uniform
      int last = dcl - 1;
      for (int p = 0; p < dcl; p += 16) {
        unsigned v[16];
#pragma unroll
        for (int j = 0; j < 16; j++) {
          int s = __shfl(slot[i], min(p + j, last), 64);
          v[j] = xb[(size_t)s * 64 + lane];      // 256B/row coalesced, no branch
        }
#pragma unroll
        for (int j = 0; j < 16; j++) {
          unsigned vj = (p + j <= last) ? v[j] : 0u;
          a0 += bflo(vj); a1 += bfhi(vj);
        }
      }
    }
    float inv = 1.f / (float)max(deg[i], 1);
    unsigned pk = ((unsigned)f2bf(a1 * inv) << 16) | f2bf(a0 * inv);
    ((unsigned*)&sA[wv * 16 + i][0])[lane]   = pk;      // agg half: k in [0,128)
    ((unsigned*)&sA[wv * 16 + i][128])[lane] = xr[i];   // x half:   k in [128,256)
  }

  // ---- MFMA: A from my LDS rows, B from k-major WT in global (L2-hot) ----
  const int m = lane & 15;
  const int q = lane >> 4;

  f32x4 acc[M / 16];
#pragma unroll
  for (int c = 0; c < M / 16; c++) acc[c] = {0.f, 0.f, 0.f, 0.f};

#pragma unroll
  for (int ks = 0; ks < 8; ks++) {
    short8 a = *(const short8*)&sA[wv * 16 + m][ks * 32 + q * 8];   // A[m][q*8+j]
#pragma unroll
    for (int c = 0; c < M / 16; c++) {
      // B[k=q*8+j][n=c*16+m] = WT[n][k], contiguous 16B in k
      short8 b = *(const short8*)(WT + (size_t)(c * 16 + m) * 256 + ks * 32 + q * 8);
      acc[c] = __builtin_amdgcn_mfma_f32_16x16x32_bf16(a, b, acc[c], 0, 0, 0);
    }
  }

  // ---- epilogue: restage C through my (dead) sA rows -> full-line stores ----
#pragma unroll
  for (int c = 0; c < M / 16; c++) {
    int col = c * 16 + m;
    float bc = bias[col];
#pragma unroll
    for (int r = 0; r < 4; r++) {
      int lr = wv * 16 + q * 4 + r;               // D[row=q*4+r][col=m]
      float v = acc[c][r] + bc;
      if (RELU) v = fmaxf(v, 0.f);
      if constexpr (sizeof(OutT) == 2) sA[lr][col] = f2bf(v);
      else ((float*)&sA[lr][0])[col] = v;
    }
  }
#pragma unroll
  for (int it = 0; it < 4; it++) {
    int idx = it * 64 + lane;                     // 16 rows x 16 chunks of 16B
    int rr = idx >> 4, cc = idx & 15;
    int node = node0 + wv * 16 + rr;
    if (node < NN) {
      uint4 v = *(const uint4*)((const char*)&sA[wv * 16 + rr][0] + cc * 16);
      *(uint4*)((char*)(out + (size_t)node * M) + cc * 16) = v;
    }
  }
}

extern "C" void kernel_launch(void* const* d_in, const int* in_sizes, int n_in,
                              void* d_out, int out_size, void* d_ws, size_t ws_size,
                              hipStream_t stream) {
  const float* x   = (const float*)d_in[0];
  const int*   ei  = (const int*)d_in[1];
  const float* W1l = (const float*)d_in[2];
  const float* b1  = (const float*)d_in[3];
  const float* W1r = (const float*)d_in[4];
  const float* W2l = (const float*)d_in[5];
  const float* b2  = (const float*)d_in[6];
  const float* W2r = (const float*)d_in[7];
  float* out = (float*)d_out;

  // ws: cnt 0.5MB | buck 25.6MB | xbf 12.8MB | h 12.8MB | WT1 | WT2
  char* ws = (char*)d_ws;
  int* cnt  = (int*)ws;                                   ws += (512 << 10);
  int* buck = (int*)ws;                                   ws += (size_t)NN * MAXDEG * 4;
  unsigned* xbf = (unsigned*)ws;                          ws += (size_t)NN * 64 * 4;
  unsigned* hb = (unsigned*)ws;                           ws += (size_t)NN * 64 * 4;
  unsigned short* WT1 = (unsigned short*)ws;              ws += 128 * 256 * 2;
  unsigned short* WT2 = (unsigned short*)ws;              ws += 64 * 256 * 2;

  const int* src = ei;        // edge_index[0]
  const int* dst = ei + NE;   // edge_index[1]

  hipMemsetAsync(cnt, 0, (size_t)NN * 4, stream);
  build_buckets<<<NSLICE * (NE / CHUNK), 256, 0, stream>>>(src, dst, cnt, buck);
  to_bf16<<<(NN * 32 + 255) / 256, 256, 0, stream>>>(x, xbf);
  transpose_w<<<192, 256, 0, stream>>>(W1l, W1r, W2l, W2r, WT1, WT2);

  // layer 1: h = relu([mean|x] @ [W1l;W1r] + b1), bf16
  sage_fused<128, true, unsigned short><<<(NN + 63) / 64, 256, 0, stream>>>(
      xbf, cnt, buck, WT1, b1, (unsigned short*)hb);

  // layer 2: out = [mean|h] @ [W2l;W2r] + b2, f32
  sage_fused<64, false, float><<<(NN + 63) / 64, 256, 0, stream>>>(
      hb, cnt, buck, WT2, b2, out);
}